// Round 10
// baseline (188.578 us; speedup 1.0000x reference)
//
#include <hip/hip_runtime.h>
#include <hip/hip_bf16.h>

#define BIG 1e30f

typedef __attribute__((ext_vector_type(8))) short short8;
typedef __attribute__((ext_vector_type(4))) float f32x4;

// Forces the preceding ds_read batch to complete HERE and stops the scheduler
// from moving register-only compute above the wait (guide rule #18).
#define LGKM_FENCE() do { asm volatile("s_waitcnt lgkmcnt(0)" ::: "memory"); \
                          __builtin_amdgcn_sched_barrier(0); } while (0)
#define SCHED_FENCE() __builtin_amdgcn_sched_barrier(0)

__device__ __forceinline__ unsigned pk_bf16(float lo, float hi) {
    unsigned r;
    asm("v_cvt_pk_bf16_f32 %0, %1, %2" : "=v"(r) : "v"(lo), "v"(hi));
    return r;
}

// 8 consecutive-k f32 values -> one bf16x8 MFMA fragment (k-major)
__device__ __forceinline__ short8 make_frag(float4 a, float4 c) {
    union { unsigned u[4]; short8 s; } cv;
    cv.u[0] = pk_bf16(a.x, a.y);
    cv.u[1] = pk_bf16(a.z, a.w);
    cv.u[2] = pk_bf16(c.x, c.y);
    cv.u[3] = pk_bf16(c.z, c.w);
    return cv.s;
}

// shfl_up(v,1) via DPP wave_shr:1 (VALU pipe; validated round 7, absmax 0.0).
__device__ __forceinline__ float dpp_shr1(float v) {
    int o = __builtin_amdgcn_update_dpp(__float_as_int(v), __float_as_int(v),
                                        0x138, 0xf, 0xf, false);
    return __int_as_float(o);
}

// Fused pairwise-sqeuclidean (bf16 MFMA) + DTW, one block per batch.
// 8 waves; wave ti owns rows [ti*64, ti*64+64). Tiles pipelined over 15
// anti-diagonal stages of the 8x8 tile grid.
// ROUND 10 = ROUND 9 step semantics verbatim, with the per-chunk dv LDS
// prefetch replaced by a once-per-stage skew-load of the lane's D row into
// 64 registers (dreg[q] = D[l][(q-l)&63], so step kk reads dreg[kk&63],
// compile-time). Chunk loop fully unrolled (static dreg/rvb indexing);
// stage loop stays rolled (I$); rowv prefetch keeps the r9 fence pinning.
// colnext cndmask dropped: act-mask freezes r1 at its c==63 value.
__global__ __launch_bounds__(512, 1) void dtw_fused(const float* __restrict__ x,
                                                    const float* __restrict__ y,
                                                    float* __restrict__ out)
{
    __shared__ float Dt[8][4096];      // per-wave 64x64 f32 D-tile, XOR-swizzled
    __shared__ float y2s[512];         // per-batch y row sumsq
    __shared__ float rowA[3][8][65];   // [parity][tj][0]=corner, [1+j]=bottom row

    const int b   = blockIdx.x;
    const int tid = threadIdx.x;
    const int w   = tid >> 6;          // wave id == tile row ti
    const int l   = tid & 63;

    const float* xb = x + (size_t)b * 512 * 64;
    const float* yb = y + (size_t)b * 512 * 64;

    // ---------- prologue: y2 (one row per thread) ----------
    {
        const float4* yr = reinterpret_cast<const float4*>(yb + (size_t)tid * 64);
        float s = 0.f;
        #pragma unroll
        for (int q = 0; q < 16; ++q) {
            float4 v = yr[q];
            s += v.x*v.x + v.y*v.y + v.z*v.z + v.w*v.w;
        }
        y2s[tid] = s;
    }
    // rowA init: BIG everywhere except corner for tile (0,0): rowA[2][0][0]=0
    for (int i = tid; i < 3*8*65; i += 512) {
        ((float*)rowA)[i] = (i == 2*8*65) ? 0.0f : BIG;
    }

    // ---------- prologue: A fragments (bf16) + x2 ----------
    const int lr = l & 15;             // row-in-subtile (A) / col-in-subtile (B,C)
    const int lg = l >> 4;             // k-group / C row-group
    short8 afr[4][2];
    float  x2c[4][4];                  // x2 at C-layout rows: mi*16 + lg*4 + i
    {
        float x2f[4];
        #pragma unroll
        for (int mi = 0; mi < 4; ++mi) {
            float part = 0.f;
            #pragma unroll
            for (int ks = 0; ks < 2; ++ks) {
                const float* rp = xb + (size_t)(w*64 + mi*16 + lr) * 64 + ks*32 + lg*8;
                float4 a0 = *reinterpret_cast<const float4*>(rp);
                float4 a1 = *reinterpret_cast<const float4*>(rp + 4);
                afr[mi][ks] = make_frag(a0, a1);
                part += a0.x*a0.x + a0.y*a0.y + a0.z*a0.z + a0.w*a0.w
                      + a1.x*a1.x + a1.y*a1.y + a1.z*a1.z + a1.w*a1.w;
            }
            part += __shfl_xor(part, 16);
            part += __shfl_xor(part, 32);
            x2f[mi] = part;            // sumsq of row mi*16 + (l&15), all 4 groups
        }
        #pragma unroll
        for (int mi = 0; mi < 4; ++mi)
            #pragma unroll
            for (int i = 0; i < 4; ++i)
                x2c[mi][i] = __shfl(x2f[mi], lg*4 + i);
    }

    float* Dw = Dt[w];
    const int xr4 = (l & 7) << 2;      // float-index XOR swizzle for row l
    const int rowbase = l << 6;
    const int nl = (64 - l) & 63;
    float colreg = BIG;                // R[w*64+l][tj*64-1] carried across tiles

    #pragma unroll 1
    for (int s = 0; s < 15; ++s) {
        __syncthreads();
        const int tj = s - w;
        if (tj < 0 || tj > 7) continue;
        const int j0 = tj * 64;

        // ---------- GEMM: D-tile via MFMA ----------
        f32x4 acc[4][4] = {};
        #pragma unroll
        for (int ni = 0; ni < 4; ++ni) {
            const float* rp = yb + (size_t)(j0 + ni*16 + lr) * 64 + lg*8;
            float4 b0 = *reinterpret_cast<const float4*>(rp);
            float4 b1 = *reinterpret_cast<const float4*>(rp + 4);
            float4 b2 = *reinterpret_cast<const float4*>(rp + 32);
            float4 b3 = *reinterpret_cast<const float4*>(rp + 36);
            short8 bf0 = make_frag(b0, b1);
            short8 bf1 = make_frag(b2, b3);
            #pragma unroll
            for (int mi = 0; mi < 4; ++mi) {
                acc[mi][ni] = __builtin_amdgcn_mfma_f32_16x16x32_bf16(afr[mi][0], bf0, acc[mi][ni], 0, 0, 0);
                acc[mi][ni] = __builtin_amdgcn_mfma_f32_16x16x32_bf16(afr[mi][1], bf1, acc[mi][ni], 0, 0, 0);
            }
        }
        // epilogue: D = x2 + y2 - 2xy -> swizzled LDS tile (2-way banks: free)
        #pragma unroll
        for (int ni = 0; ni < 4; ++ni) {
            float y2v = y2s[j0 + ni*16 + lr];
            #pragma unroll
            for (int mi = 0; mi < 4; ++mi) {
                #pragma unroll
                for (int i = 0; i < 4; ++i) {
                    int row = mi*16 + lg*4 + i;
                    int col = ni*16 + lr;
                    Dw[(row*64 + col) ^ ((row & 7) << 2)] = x2c[mi][i] + y2v - 2.0f * acc[mi][ni][i];
                }
            }
        }

        // ---------- redistribute: skew-load row l of D into registers ----------
        // dreg[q] = D[l][(q-l)&63] -> step kk reads dreg[kk&63] (static index)
        float dreg[64];
        #pragma unroll
        for (int q = 0; q < 64; ++q) {
            int t = (q + nl) & 63;
            dreg[q] = Dw[rowbase + (t ^ xr4)];
        }

        // ---------- DTW over the tile: 128 steps, 8 unrolled chunks ----------
        const float* rowR = rowA[(s + 2) % 3][tj];   // parity (s-1)%3
        float*       rowW = rowA[s % 3][tj];

        if (tj == 0 && l == 0) rowW[0] = BIG;        // corner for consumer (w+1,0)

        float r1 = colreg;     // R[row][c-1] once active; colreg until then
        float r2 = BIG;
        float saved = rowR[0]; // up-row[j-1]; starts at corner

        float rvb[2][16];
        #pragma unroll
        for (int u = 0; u < 16; ++u) rvb[0][u] = rowR[1 + u];   // chunk 0
        LGKM_FENCE();                                // dreg + rvb[0] complete

        #pragma unroll
        for (int ch = 0; ch < 8; ++ch) {
            if (ch < 7) {                            // prefetch next chunk's rowv
                #pragma unroll
                for (int u = 0; u < 16; ++u)
                    rvb[(ch + 1) & 1][u] = rowR[1 + (((ch + 1) * 16 + u) & 63)];
            }
            SCHED_FENCE();
            float rw[16];
            #pragma unroll
            for (int u = 0; u < 16; ++u) {
                const int kk = ch * 16 + u;
                int   c    = kk - l;
                float rowv = rvb[ch & 1][u];
                float dv   = dreg[kk & 63];
                float up   = dpp_shr1(r1);
                float dg   = dpp_shr1(r2);
                float pu   = (l == 0) ? rowv  : up;   // R[row-1][c]
                float pd   = (l == 0) ? saved : dg;   // R[row-1][c-1]
                float nv   = dv + fminf(fminf(pd, pu), r1);
                bool  act  = ((unsigned)c) < 64u;
                r2 = act ? r1 : r2;
                r1 = act ? nv : r1;                   // freezes at c==63 value
                rw[u] = nv;                           // buffered bottom-row value
                saved = rowv;
            }
            if (l == 63) {                            // one store block per chunk
                #pragma unroll
                for (int u = 0; u < 16; ++u) {
                    int kk = ch * 16 + u;
                    if ((unsigned)(kk - 63) < 64u) rowW[kk - 62] = rw[u];
                }
            }
            LGKM_FENCE();                             // next rvb (and stores) done
        }
        colreg = r1;                                  // frozen c==63 value
        if (l == 63 && tj < 7) rowA[(s + 1) % 3][tj + 1][0] = r1;  // corner
    }

    if (w == 7 && l == 63) out[b] = colreg;   // R[511][511]
}

extern "C" void kernel_launch(void* const* d_in, const int* in_sizes, int n_in,
                              void* d_out, int out_size, void* d_ws, size_t ws_size,
                              hipStream_t stream) {
    (void)in_sizes; (void)n_in; (void)d_ws; (void)ws_size; (void)out_size;
    const float* x = (const float*)d_in[0];
    const float* y = (const float*)d_in[1];
    float* out = (float*)d_out;
    dtw_fused<<<128, 512, 0, stream>>>(x, y, out);
}